// Round 1
// baseline (639.945 us; speedup 1.0000x reference)
//
#include <hip/hip_runtime.h>
#include <cstdint>
#include <cstddef>

#define D_ 1024
#define S_ 2048
#define B_ 32

typedef float f32x4 __attribute__((ext_vector_type(4)));
typedef __bf16 v8bf __attribute__((ext_vector_type(8)));

__device__ __forceinline__ unsigned short f2bf_rne(float f) {
  unsigned int u = __float_as_uint(f);
  u = (u + 0x7FFFu + ((u >> 16) & 1u)) >> 16;
  return (unsigned short)u;
}

__device__ __forceinline__ float tanh_fast(float x) {
  float ax = __builtin_fabsf(x);
  float e = __expf(2.0f * ax);                       // overflows to inf for big x -> r -> 1
  float r = 1.0f - 2.0f * __builtin_amdgcn_rcpf(e + 1.0f);
  return __builtin_copysignf(r, x);
}

// ---------------- K0: W_c fp32 -> bf16 (2 MB, L2-resident afterwards) ----------------
__global__ void k_cvt_wc(const float* __restrict__ wc, unsigned short* __restrict__ out) {
  int e = blockIdx.x, t = threadIdx.x;
  float4 v = ((const float4*)(wc + (size_t)e * D_))[t];
  ushort4 o;
  o.x = f2bf_rne(v.x); o.y = f2bf_rne(v.y); o.z = f2bf_rne(v.z); o.w = f2bf_rne(v.w);
  ((ushort4*)(out + (size_t)e * D_))[t] = o;
}

// ---------------- K1: tadd[b,e] = x[b,:] . W_in[e,:] + b_c[e] ----------------
__global__ void k_target(const float* __restrict__ x, const float* __restrict__ win,
                         const float* __restrict__ bc, float* __restrict__ tadd) {
  __shared__ float wl[D_];
  int e = blockIdx.x, t = threadIdx.x;
  ((float4*)wl)[t] = ((const float4*)(win + (size_t)e * D_))[t];
  __syncthreads();
  int w = t >> 6, lane = t & 63;
  float bce = bc[e];
  for (int bb = w; bb < B_; bb += 4) {
    const float* xr = x + (size_t)bb * D_ + lane * 16;
    const float* wr = wl + lane * 16;
    float p = 0.f;
#pragma unroll
    for (int c = 0; c < 4; ++c) {
      float4 xv = ((const float4*)xr)[c];
      float4 wv = ((const float4*)wr)[c];
      p += xv.x * wv.x + xv.y * wv.y + xv.z * wv.z + xv.w * wv.w;
    }
#pragma unroll
    for (int off = 32; off; off >>= 1) p += __shfl_xor(p, off, 64);
    if (lane == 0) tadd[(size_t)bb * D_ + e] = p + bce;
  }
}

// ---------------- K2: fused scores GEMM ----------------
// part[pslice][b][s], pslice = e_tile*2 + e_half (16 slices), summed in K3.
__global__ __launch_bounds__(256, 2) void k_scores(
    const float* __restrict__ ctx, const unsigned short* __restrict__ wcb,
    const float* __restrict__ tadd, const float* __restrict__ wv,
    float* __restrict__ part) {
  __shared__ unsigned short As[128 * 32];
  __shared__ unsigned short Bs[128 * 32];
  int g = blockIdx.x;
  int xcd = g & 7;
  int j = g >> 3;
  int stile = xcd * 64 + (j >> 3);   // XCD-grouped: 8 e-tiles of one s-tile adjacent per XCD
  int et = j & 7;
  int b = stile >> 4;
  int s0 = (stile & 15) << 7;
  int e0 = et << 7;
  int t = threadIdx.x;
  int w = t >> 6, lane = t & 63;

  f32x4 acc[4][4];
#pragma unroll
  for (int i = 0; i < 4; ++i)
#pragma unroll
    for (int jj = 0; jj < 4; ++jj) acc[i][jj] = (f32x4){0.f, 0.f, 0.f, 0.f};

  const int m = lane & 15, q = lane >> 4;
  const int ws_ = (w & 1) << 6, we_ = (w >> 1) << 6;

  const int brow = lane >> 2;        // 16 rows per DMA issue
  const int bcol = (lane & 3) << 3;  // 8 bf16 = 16B per lane
  const int arow = t >> 3;           // 32 rows per pass, 4 passes
  const int acol = (t & 7) << 2;     // 4 fp32 per thread

  const size_t ctx_base = ((size_t)b * S_ + s0) * D_;
  const size_t wc_base = (size_t)e0 * D_;

  for (int kt = 0; kt < 32; ++kt) {
    const int k0 = kt << 5;
    __syncthreads();
    // B tile: direct-to-LDS DMA, 16B/lane, wave-uniform LDS base + lane*16
#pragma unroll
    for (int p = 0; p < 2; ++p) {
      int row = (w << 5) + (p << 4) + brow;
      const unsigned short* gp = wcb + wc_base + (size_t)row * D_ + k0 + bcol;
      unsigned short* lp = Bs + (((w << 5) + (p << 4)) << 5);
      __builtin_amdgcn_global_load_lds(
          (const __attribute__((address_space(1))) unsigned int*)gp,
          (__attribute__((address_space(3))) unsigned int*)lp, 16, 0, 0);
    }
    // A tile: fp32 load + inline bf16 convert + LDS write
#pragma unroll
    for (int p = 0; p < 4; ++p) {
      int row = (p << 5) + arow;
      float4 v = *(const float4*)(ctx + ctx_base + (size_t)row * D_ + k0 + acol);
      ushort4 o;
      o.x = f2bf_rne(v.x); o.y = f2bf_rne(v.y);
      o.z = f2bf_rne(v.z); o.w = f2bf_rne(v.w);
      *(ushort4*)(As + (row << 5) + acol) = o;
    }
    __syncthreads();
    v8bf a[4], bf[4];
#pragma unroll
    for (int i = 0; i < 4; ++i)
      a[i] = *(const v8bf*)(As + ((ws_ + (i << 4) + m) << 5) + (q << 3));
#pragma unroll
    for (int jj = 0; jj < 4; ++jj)
      bf[jj] = *(const v8bf*)(Bs + ((we_ + (jj << 4) + m) << 5) + (q << 3));
#pragma unroll
    for (int i = 0; i < 4; ++i)
#pragma unroll
      for (int jj = 0; jj < 4; ++jj)
        acc[i][jj] = __builtin_amdgcn_mfma_f32_16x16x32_bf16(a[i], bf[jj], acc[i][jj], 0, 0, 0);
  }

  // epilogue: tanh(acc + tadd[b,e]) * w_v[e], reduce over e within wave
  float sp[4][4];
#pragma unroll
  for (int i = 0; i < 4; ++i)
#pragma unroll
    for (int r = 0; r < 4; ++r) sp[i][r] = 0.f;
#pragma unroll
  for (int jj = 0; jj < 4; ++jj) {
    int e = e0 + we_ + (jj << 4) + m;
    float ta = tadd[(size_t)b * D_ + e];
    float wve = wv[e];
#pragma unroll
    for (int i = 0; i < 4; ++i)
#pragma unroll
      for (int r = 0; r < 4; ++r)
        sp[i][r] += tanh_fast(acc[i][jj][r] + ta) * wve;
  }
#pragma unroll
  for (int off = 1; off < 16; off <<= 1)
#pragma unroll
    for (int i = 0; i < 4; ++i)
#pragma unroll
      for (int r = 0; r < 4; ++r) sp[i][r] += __shfl_xor(sp[i][r], off, 64);
  if (m == 0) {
    int ps = (et << 1) + (w >> 1);
    float* dst = part + ((size_t)ps * B_ + b) * S_ + s0 + ws_ + (q << 2);
#pragma unroll
    for (int i = 0; i < 4; ++i)
#pragma unroll
      for (int r = 0; r < 4; ++r) dst[(i << 4) + r] = sp[i][r];
  }
}

// ---------------- K3: sum 16 partial slices, softmax over S, write attn_w ----------------
__global__ void k_softmax(const float* __restrict__ part, float* __restrict__ attn) {
  __shared__ float red[4];
  int b = blockIdx.x, t = threadIdx.x;
  int w = t >> 6, lane = t & 63;
  float sc[8];
#pragma unroll
  for (int u = 0; u < 8; ++u) {
    int s = t + (u << 8);
    float v = 0.f;
#pragma unroll
    for (int p = 0; p < 16; ++p) v += part[((size_t)p * B_ + b) * S_ + s];
    sc[u] = v;
  }
  float mx = sc[0];
#pragma unroll
  for (int u = 1; u < 8; ++u) mx = fmaxf(mx, sc[u]);
#pragma unroll
  for (int off = 32; off; off >>= 1) mx = fmaxf(mx, __shfl_xor(mx, off, 64));
  if (lane == 0) red[w] = mx;
  __syncthreads();
  mx = fmaxf(fmaxf(red[0], red[1]), fmaxf(red[2], red[3]));
  float sum = 0.f;
#pragma unroll
  for (int u = 0; u < 8; ++u) { sc[u] = __expf(sc[u] - mx); sum += sc[u]; }
#pragma unroll
  for (int off = 32; off; off >>= 1) sum += __shfl_xor(sum, off, 64);
  __syncthreads();
  if (lane == 0) red[w] = sum;
  __syncthreads();
  sum = red[0] + red[1] + red[2] + red[3];
  float rv = 1.0f / sum;
#pragma unroll
  for (int u = 0; u < 8; ++u) attn[(size_t)b * S_ + t + (u << 8)] = sc[u] * rv;
}

// ---------------- K4: weighted[b,d] = sum_s attn_w[b,s] * context[b,s,d] ----------------
__global__ void k_weighted(const float* __restrict__ ctx, const float* __restrict__ attn,
                           float* __restrict__ wout) {
  __shared__ float al[S_];
  __shared__ float red[16][64];
  int bid = blockIdx.x;
  int b = bid >> 4, d0 = (bid & 15) << 6;
  int t = threadIdx.x;
#pragma unroll
  for (int u = 0; u < 8; ++u) al[t + (u << 8)] = attn[(size_t)b * S_ + t + (u << 8)];
  __syncthreads();
  int sway = t >> 4, dl = (t & 15) << 2;
  f32x4 acc = {0.f, 0.f, 0.f, 0.f};
  const float* base = ctx + (size_t)b * S_ * D_ + d0 + dl;
  for (int s = sway; s < S_; s += 16) {
    float wgt = al[s];
    float4 c = *(const float4*)(base + (size_t)s * D_);
    acc.x += wgt * c.x; acc.y += wgt * c.y; acc.z += wgt * c.z; acc.w += wgt * c.w;
  }
  red[sway][dl] = acc.x; red[sway][dl + 1] = acc.y;
  red[sway][dl + 2] = acc.z; red[sway][dl + 3] = acc.w;
  __syncthreads();
  if (t < 64) {
    float v = 0.f;
#pragma unroll
    for (int p = 0; p < 16; ++p) v += red[p][t];
    wout[(size_t)b * D_ + d0 + t] = v;
  }
}

// ---------------- K5: h[b,j] = tanh( [weighted|x][b,:] . W_out[j,:] ) ----------------
__global__ void k_out(const float* __restrict__ wgt, const float* __restrict__ x,
                      const float* __restrict__ wo, float* __restrict__ out) {
  __shared__ float wl[2 * D_];
  int jrow = blockIdx.x, t = threadIdx.x;
#pragma unroll
  for (int u = 0; u < 2; ++u)
    ((float4*)wl)[t + (u << 8)] = ((const float4*)(wo + (size_t)jrow * 2 * D_))[t + (u << 8)];
  __syncthreads();
  int w = t >> 6, lane = t & 63;
  for (int bb = w; bb < B_; bb += 4) {
    const float* src = (lane < 32) ? (wgt + (size_t)bb * D_ + (lane << 5))
                                   : (x + (size_t)bb * D_ + ((lane - 32) << 5));
    const float* wr = wl + (lane << 5);
    float p = 0.f;
#pragma unroll
    for (int c = 0; c < 8; ++c) {
      float4 a = ((const float4*)src)[c];
      float4 ww = ((const float4*)wr)[c];
      p += a.x * ww.x + a.y * ww.y + a.z * ww.z + a.w * ww.w;
    }
#pragma unroll
    for (int off = 32; off; off >>= 1) p += __shfl_xor(p, off, 64);
    if (lane == 0) out[(size_t)bb * D_ + jrow] = tanh_fast(p);
  }
}

extern "C" void kernel_launch(void* const* d_in, const int* in_sizes, int n_in,
                              void* d_out, int out_size, void* d_ws, size_t ws_size,
                              hipStream_t stream) {
  const float* x   = (const float*)d_in[0];
  const float* ctx = (const float*)d_in[1];
  const float* win = (const float*)d_in[2];
  const float* wc  = (const float*)d_in[3];
  const float* bc  = (const float*)d_in[4];
  const float* wv  = (const float*)d_in[5];
  const float* wo  = (const float*)d_in[6];
  float* out = (float*)d_out;  // [0,32768): h_tilde, [32768,98304): attn_w

  char* ws = (char*)d_ws;
  float* tadd = (float*)ws;                                          // 128 KiB
  float* part = (float*)(ws + 131072);                               // 4 MiB
  float* wgt  = (float*)(ws + 131072 + 4194304);                     // 128 KiB
  unsigned short* wcb = (unsigned short*)(ws + 131072 + 4194304 + 131072);  // 2 MiB

  k_cvt_wc  <<<1024, 256, 0, stream>>>(wc, wcb);
  k_target  <<<1024, 256, 0, stream>>>(x, win, bc, tadd);
  k_scores  <<<4096, 256, 0, stream>>>(ctx, wcb, tadd, wv, part);
  k_softmax <<<32,   256, 0, stream>>>(part, out + 32768);
  k_weighted<<<512,  256, 0, stream>>>(ctx, out + 32768, wgt);
  k_out     <<<1024, 256, 0, stream>>>(wgt, x, wo, out);
}

// Round 2
// 617.149 us; speedup vs baseline: 1.0369x; 1.0369x over previous
//
#include <hip/hip_runtime.h>
#include <cstdint>
#include <cstddef>

#define D_ 1024
#define S_ 2048
#define B_ 32

typedef float f32x4 __attribute__((ext_vector_type(4)));
typedef __bf16 v8bf __attribute__((ext_vector_type(8)));

__device__ __forceinline__ unsigned short f2bf_rne(float f) {
  unsigned int u = __float_as_uint(f);
  u = (u + 0x7FFFu + ((u >> 16) & 1u)) >> 16;
  return (unsigned short)u;
}

// pack two fp32 (already +0x8000 rounded) into packed bf16x2 via byte-perm
__device__ __forceinline__ unsigned int bfpack(float f0, float f1) {
  unsigned int u0 = __float_as_uint(f0) + 0x8000u;
  unsigned int u1 = __float_as_uint(f1) + 0x8000u;
  return __builtin_amdgcn_perm(u1, u0, 0x07060302u);  // lo=hi16(u0), hi=hi16(u1)
}

__device__ __forceinline__ float tanh_fast(float x) {
  float ax = __builtin_fabsf(x);
  float e = __expf(2.0f * ax);
  float r = 1.0f - 2.0f * __builtin_amdgcn_rcpf(e + 1.0f);
  return __builtin_copysignf(r, x);
}

// ---------------- K0: W_c fp32 -> bf16 (2 MB, L2/L3-resident afterwards) ----------------
__global__ void k_cvt_wc(const float* __restrict__ wc, unsigned short* __restrict__ out) {
  int e = blockIdx.x, t = threadIdx.x;
  float4 v = ((const float4*)(wc + (size_t)e * D_))[t];
  ushort4 o;
  o.x = f2bf_rne(v.x); o.y = f2bf_rne(v.y); o.z = f2bf_rne(v.z); o.w = f2bf_rne(v.w);
  ((ushort4*)(out + (size_t)e * D_))[t] = o;
}

// ---------------- K1: tadd[b,e] = x[b,:] . W_in[e,:] + b_c[e] ----------------
__global__ void k_target(const float* __restrict__ x, const float* __restrict__ win,
                         const float* __restrict__ bc, float* __restrict__ tadd) {
  __shared__ float wl[D_];
  int e = blockIdx.x, t = threadIdx.x;
  ((float4*)wl)[t] = ((const float4*)(win + (size_t)e * D_))[t];
  __syncthreads();
  int w = t >> 6, lane = t & 63;
  float bce = bc[e];
  for (int bb = w; bb < B_; bb += 4) {
    const float* xr = x + (size_t)bb * D_ + lane * 16;
    const float* wr = wl + lane * 16;
    float p = 0.f;
#pragma unroll
    for (int c = 0; c < 4; ++c) {
      float4 xv = ((const float4*)xr)[c];
      float4 wv = ((const float4*)wr)[c];
      p += xv.x * wv.x + xv.y * wv.y + xv.z * wv.z + xv.w * wv.w;
    }
#pragma unroll
    for (int off = 32; off; off >>= 1) p += __shfl_xor(p, off, 64);
    if (lane == 0) tadd[(size_t)bb * D_ + e] = p + bce;
  }
}

// ---------------- K2: fused scores GEMM ----------------
// part[pslice][b][s], pslice = e_tile*2 + e_half (16 slices), summed in K3.
__global__ __launch_bounds__(256, 2) void k_scores(
    const float* __restrict__ ctx, const unsigned short* __restrict__ wcb,
    const float* __restrict__ tadd, const float* __restrict__ wv,
    float* __restrict__ part) {
  __shared__ unsigned short As[128 * 32];
  __shared__ unsigned short Bs[128 * 32];
  int g = blockIdx.x;
  int xcd = g & 7;
  int j = g >> 3;
  int stile = xcd * 64 + (j >> 3);   // XCD-grouped: 8 e-tiles of one s-tile adjacent per XCD
  int et = j & 7;
  int b = stile >> 4;
  int s0 = (stile & 15) << 7;
  int e0 = et << 7;
  int t = threadIdx.x;
  int w = t >> 6, lane = t & 63;

  f32x4 acc[4][4];
#pragma unroll
  for (int i = 0; i < 4; ++i)
#pragma unroll
    for (int jj = 0; jj < 4; ++jj) acc[i][jj] = (f32x4){0.f, 0.f, 0.f, 0.f};

  const int m = lane & 15, q = lane >> 4;
  const int ws_ = (w & 1) << 6, we_ = (w >> 1) << 6;

  const int brow = lane >> 2;        // B DMA: 16 rows per issue
  const int bcol = (lane & 3) << 3;  // 8 bf16 = 16B per lane
  const int arow = t >> 2;           // A: 64 rows per pass, 2 passes
  const int acolf = (t & 3) << 3;    // 8 fp32 per thread (32B) -> 8 bf16 (16B)

  const size_t ctx_base = ((size_t)b * S_ + s0) * D_;
  const size_t wc_base = (size_t)e0 * D_;

  for (int kt = 0; kt < 32; ++kt) {
    const int k0 = kt << 5;
    __syncthreads();
    // B tile: direct-to-LDS DMA, 16B/lane, wave-uniform LDS base + lane*16
#pragma unroll
    for (int p = 0; p < 2; ++p) {
      int row = (w << 5) + (p << 4) + brow;
      const unsigned short* gp = wcb + wc_base + (size_t)row * D_ + k0 + bcol;
      unsigned short* lp = Bs + (((w << 5) + (p << 4)) << 5);
      __builtin_amdgcn_global_load_lds(
          (const __attribute__((address_space(1))) unsigned int*)gp,
          (__attribute__((address_space(3))) unsigned int*)lp, 16, 0, 0);
    }
    // A tile: fp32 load + cheap round + perm-pack + b128 LDS write (2 passes)
#pragma unroll
    for (int p = 0; p < 2; ++p) {
      int row = (p << 6) + arow;
      const float* gp = ctx + ctx_base + (size_t)row * D_ + k0 + acolf;
      float4 v0 = *(const float4*)gp;
      float4 v1 = *(const float4*)(gp + 4);
      uint4 o;
      o.x = bfpack(v0.x, v0.y);
      o.y = bfpack(v0.z, v0.w);
      o.z = bfpack(v1.x, v1.y);
      o.w = bfpack(v1.z, v1.w);
      *(uint4*)(As + (row << 5) + acolf) = o;
    }
    __syncthreads();
    v8bf a[4], bf[4];
#pragma unroll
    for (int i = 0; i < 4; ++i)
      a[i] = *(const v8bf*)(As + ((ws_ + (i << 4) + m) << 5) + (q << 3));
#pragma unroll
    for (int jj = 0; jj < 4; ++jj)
      bf[jj] = *(const v8bf*)(Bs + ((we_ + (jj << 4) + m) << 5) + (q << 3));
#pragma unroll
    for (int i = 0; i < 4; ++i)
#pragma unroll
      for (int jj = 0; jj < 4; ++jj)
        acc[i][jj] = __builtin_amdgcn_mfma_f32_16x16x32_bf16(a[i], bf[jj], acc[i][jj], 0, 0, 0);
  }

  // epilogue: tanh(acc + tadd[b,e]) * w_v[e], reduce over e within wave
  float sp[4][4];
#pragma unroll
  for (int i = 0; i < 4; ++i)
#pragma unroll
    for (int r = 0; r < 4; ++r) sp[i][r] = 0.f;
#pragma unroll
  for (int jj = 0; jj < 4; ++jj) {
    int e = e0 + we_ + (jj << 4) + m;
    float ta = tadd[(size_t)b * D_ + e];
    float wve = wv[e];
#pragma unroll
    for (int i = 0; i < 4; ++i)
#pragma unroll
      for (int r = 0; r < 4; ++r)
        sp[i][r] += tanh_fast(acc[i][jj][r] + ta) * wve;
  }
#pragma unroll
  for (int off = 1; off < 16; off <<= 1)
#pragma unroll
    for (int i = 0; i < 4; ++i)
#pragma unroll
      for (int r = 0; r < 4; ++r) sp[i][r] += __shfl_xor(sp[i][r], off, 64);
  if (m == 0) {
    int ps = (et << 1) + (w >> 1);
    float* dst = part + ((size_t)ps * B_ + b) * S_ + s0 + ws_ + (q << 2);
#pragma unroll
    for (int i = 0; i < 4; ++i)
#pragma unroll
      for (int r = 0; r < 4; ++r) dst[(i << 4) + r] = sp[i][r];
  }
}

// ---------------- K3: sum 16 partial slices, softmax over S, write attn_w ----------------
__global__ void k_softmax(const float* __restrict__ part, float* __restrict__ attn) {
  __shared__ float red[4];
  int b = blockIdx.x, t = threadIdx.x;
  int w = t >> 6, lane = t & 63;
  float sc[8];
#pragma unroll
  for (int u = 0; u < 8; ++u) {
    int s = t + (u << 8);
    float v = 0.f;
#pragma unroll
    for (int p = 0; p < 16; ++p) v += part[((size_t)p * B_ + b) * S_ + s];
    sc[u] = v;
  }
  float mx = sc[0];
#pragma unroll
  for (int u = 1; u < 8; ++u) mx = fmaxf(mx, sc[u]);
#pragma unroll
  for (int off = 32; off; off >>= 1) mx = fmaxf(mx, __shfl_xor(mx, off, 64));
  if (lane == 0) red[w] = mx;
  __syncthreads();
  mx = fmaxf(fmaxf(red[0], red[1]), fmaxf(red[2], red[3]));
  float sum = 0.f;
#pragma unroll
  for (int u = 0; u < 8; ++u) { sc[u] = __expf(sc[u] - mx); sum += sc[u]; }
#pragma unroll
  for (int off = 32; off; off >>= 1) sum += __shfl_xor(sum, off, 64);
  __syncthreads();
  if (lane == 0) red[w] = sum;
  __syncthreads();
  sum = red[0] + red[1] + red[2] + red[3];
  float rv = 1.0f / sum;
#pragma unroll
  for (int u = 0; u < 8; ++u) attn[(size_t)b * S_ + t + (u << 8)] = sc[u] * rv;
}

// ---------------- K4: partial weighted sums, full-row coalesced ----------------
// grid = 32 b x 16 s-chunks (128 rows each); all 256 threads stream whole 4KB rows.
// pw[chunk][b][d]
__global__ void k_weighted(const float* __restrict__ ctx, const float* __restrict__ attn,
                           float* __restrict__ pw) {
  __shared__ float al[128];
  int bid = blockIdx.x;
  int b = bid >> 4, c = bid & 15;
  int t = threadIdx.x;
  int s0 = c << 7;
  if (t < 128) al[t] = attn[(size_t)b * S_ + s0 + t];
  __syncthreads();
  f32x4 acc = {0.f, 0.f, 0.f, 0.f};
  const float* base = ctx + ((size_t)b * S_ + s0) * D_ + (t << 2);
#pragma unroll 4
  for (int s = 0; s < 128; ++s) {
    float wgt = al[s];
    float4 v = *(const float4*)(base + (size_t)s * D_);
    acc.x += wgt * v.x; acc.y += wgt * v.y; acc.z += wgt * v.z; acc.w += wgt * v.w;
  }
  *(f32x4*)(pw + ((size_t)(c * B_ + b)) * D_ + (t << 2)) = acc;
}

// ---------------- K4b: reduce the 16 chunk partials ----------------
__global__ void k_wred(const float* __restrict__ pw, float* __restrict__ wgt) {
  int b = blockIdx.x, t = threadIdx.x;
  f32x4 v = {0.f, 0.f, 0.f, 0.f};
#pragma unroll
  for (int c = 0; c < 16; ++c) {
    f32x4 u = *(const f32x4*)(pw + ((size_t)(c * B_ + b)) * D_ + (t << 2));
    v.x += u.x; v.y += u.y; v.z += u.z; v.w += u.w;
  }
  *(f32x4*)(wgt + (size_t)b * D_ + (t << 2)) = v;
}

// ---------------- K5: h[b,j] = tanh( [weighted|x][b,:] . W_out[j,:] ) ----------------
__global__ void k_out(const float* __restrict__ wgt, const float* __restrict__ x,
                      const float* __restrict__ wo, float* __restrict__ out) {
  __shared__ float wl[2 * D_];
  int jrow = blockIdx.x, t = threadIdx.x;
#pragma unroll
  for (int u = 0; u < 2; ++u)
    ((float4*)wl)[t + (u << 8)] = ((const float4*)(wo + (size_t)jrow * 2 * D_))[t + (u << 8)];
  __syncthreads();
  int w = t >> 6, lane = t & 63;
  for (int bb = w; bb < B_; bb += 4) {
    const float* src = (lane < 32) ? (wgt + (size_t)bb * D_ + (lane << 5))
                                   : (x + (size_t)bb * D_ + ((lane - 32) << 5));
    const float* wr = wl + (lane << 5);
    float p = 0.f;
#pragma unroll
    for (int c = 0; c < 8; ++c) {
      float4 a = ((const float4*)src)[c];
      float4 ww = ((const float4*)wr)[c];
      p += a.x * ww.x + a.y * ww.y + a.z * ww.z + a.w * ww.w;
    }
#pragma unroll
    for (int off = 32; off; off >>= 1) p += __shfl_xor(p, off, 64);
    if (lane == 0) out[(size_t)bb * D_ + jrow] = tanh_fast(p);
  }
}

extern "C" void kernel_launch(void* const* d_in, const int* in_sizes, int n_in,
                              void* d_out, int out_size, void* d_ws, size_t ws_size,
                              hipStream_t stream) {
  const float* x   = (const float*)d_in[0];
  const float* ctx = (const float*)d_in[1];
  const float* win = (const float*)d_in[2];
  const float* wc  = (const float*)d_in[3];
  const float* bc  = (const float*)d_in[4];
  const float* wv  = (const float*)d_in[5];
  const float* wo  = (const float*)d_in[6];
  float* out = (float*)d_out;  // [0,32768): h_tilde, [32768,98304): attn_w

  char* ws = (char*)d_ws;
  float* tadd = (float*)ws;                                          // 128 KiB
  float* part = (float*)(ws + 131072);                               // 4 MiB
  float* pw   = part;                                                // aliases part (dead after softmax)
  float* wgt  = (float*)(ws + 131072 + 4194304);                     // 128 KiB
  unsigned short* wcb = (unsigned short*)(ws + 131072 + 4194304 + 131072);  // 2 MiB

  k_cvt_wc  <<<1024, 256, 0, stream>>>(wc, wcb);
  k_target  <<<1024, 256, 0, stream>>>(x, win, bc, tadd);
  k_scores  <<<4096, 256, 0, stream>>>(ctx, wcb, tadd, wv, part);
  k_softmax <<<32,   256, 0, stream>>>(part, out + 32768);
  k_weighted<<<512,  256, 0, stream>>>(ctx, out + 32768, pw);
  k_wred    <<<32,   256, 0, stream>>>(pw, wgt);
  k_out     <<<1024, 256, 0, stream>>>(wgt, x, wo, out);
}